// Round 9
// baseline (10263.641 us; speedup 1.0000x reference)
//
#include <hip/hip_runtime.h>
#include <math.h>

#define HH 128
#define WW 128
#define NIMG 4
#define PP 11
#define KSIM 16
#define STRIDE_S 3
#define VRAD 32
#define WINW 65             // 2V+1
#define NTASK (WINW*9)      // 585 tasks: (8-wide dc strip, drx)
#define HREF 40
#define WREF 40
#define NPOS 118            // H-P+1
#define WROWS 75            // 2V+P
#define WPITCH 84
#define NGROUP (NIMG*HREF*WREF) // 6400
#define EPS_E 30.25f        // n*alpha^2*sigma^2
#define DE_C 151.25f        // D+E
#define INFD 3.0e38f
#define RTASK 292           // c0=32, drx=32: the (0,0)-displacement candidate
#define CNP 120             // cnorm row pitch

#define FOOT 84
#define FPITCH 85
#define SPITCH 88

// ---------------------------------------------------------------------------
// Stage 0: candidate-patch squared norms (ref-independent, computed once).
// ---------------------------------------------------------------------------
__global__ __launch_bounds__(128)
void bm_norm(const float* __restrict__ y, float* __restrict__ cnorm)
{
    int n = blockIdx.x / NPOS, rr = blockIdx.x % NPOS;
    int cc = threadIdx.x;
    if (cc < NPOS) {
        const float* img = y + n * HH * WW;
        float s = 0.f;
        for (int a = 0; a < PP; a++) {
            const float* rp = &img[(rr + a) * WW + cc];
#pragma unroll
            for (int b = 0; b < PP; b++) s += rp[b] * rp[b];
        }
        cnorm[n * NPOS * CNP + rr * CNP + cc] = s;
    }
}

// ---------------------------------------------------------------------------
// Stage 1: block matching (R8 structure). dist = cnorm - 2<c,r> with cnorm
// precomputed (colsq/prefix removed from hot loop). Register top-16.
// ---------------------------------------------------------------------------
__global__ __launch_bounds__(256, 5)
void bm_kernel(const float* __restrict__ y, const float* __restrict__ cnorm,
               int* __restrict__ inds)
{
    __shared__ float win[WROWS][WPITCH];   // 25.2 KB
    __shared__ float swv[4];
    __shared__ int   swi[4];

    const int blk = blockIdx.x;
    const int n   = blk / (HREF*WREF);
    const int rem = blk % (HREF*WREF);
    const int hr  = (rem / WREF) * STRIDE_S;
    const int wr  = (rem % WREF) * STRIDE_S;
    const float* img = y + n * HH * WW;
    const float* cn  = cnorm + n * NPOS * CNP;
    const int tid = threadIdx.x;

    for (int t = tid; t < WROWS * WPITCH; t += 256) {
        int r = t / WPITCH, c = t % WPITCH;
        int gr = hr - VRAD + r, gc = wr - VRAD + c;
        float v = 0.f;
        if (c < WROWS && gr >= 0 && gr < HH && gc >= 0 && gc < WW)
            v = img[gr * WW + gc];
        win[r][c] = v;
    }
    __syncthreads();

    float d[3][8];
#pragma unroll
    for (int s = 0; s < 3; s++)
#pragma unroll
        for (int c = 0; c < 8; c++) d[s][c] = INFD;

#pragma unroll
    for (int s = 0; s < 3; s++) {
        int task = tid + (s << 8);
        if (task < NTASK) {
            int drx = task % WINW;
            int c0  = (task / WINW) * 8;
            int rr  = hr + drx - VRAD;
            bool rowok = (rr >= 0 && rr <= HH - PP);
            if (rowok) {
                float dot[8];
#pragma unroll
                for (int c = 0; c < 8; c++) dot[c] = 0.f;
                for (int a = 0; a < PP; a++) {
                    const float4* w4 = reinterpret_cast<const float4*>(&win[drx + a][c0]);
                    float4 A0 = w4[0], A1 = w4[1], A2 = w4[2], A3 = w4[3];
                    float2 A4 = *reinterpret_cast<const float2*>(&win[drx + a][c0 + 16]);
                    float wv[18] = {A0.x,A0.y,A0.z,A0.w, A1.x,A1.y,A1.z,A1.w,
                                    A2.x,A2.y,A2.z,A2.w, A3.x,A3.y,A3.z,A3.w,
                                    A4.x,A4.y};
                    const float4* r4 = reinterpret_cast<const float4*>(&win[VRAD + a][VRAD]);
                    float4 R0 = r4[0], R1 = r4[1];
                    float2 R2 = *reinterpret_cast<const float2*>(&win[VRAD + a][VRAD + 8]);
                    float  R3 = win[VRAD + a][VRAD + 10];
                    float rv[11] = {R0.x,R0.y,R0.z,R0.w, R1.x,R1.y,R1.z,R1.w,
                                    R2.x,R2.y, R3};
#pragma unroll
                    for (int b = 0; b < PP; b++) {
#pragma unroll
                        for (int c = 0; c < 8; c++)
                            dot[c] += wv[b + c] * rv[b];
                    }
                }
#pragma unroll
                for (int c = 0; c < 8; c++) {
                    int dcx = c0 + c;
                    int cc  = wr + dcx - VRAD;
                    if (dcx < WINW && cc >= 0 && cc <= WW - PP)
                        d[s][c] = cn[rr * CNP + cc] - 2.f * dot[c];
                }
            }
            if (task == RTASK) d[s][0] = -INFD;   // reference always kept
        }
    }

    float lval = INFD; int lidx = 0;
#pragma unroll
    for (int s = 0; s < 3; s++)
#pragma unroll
        for (int c = 0; c < 8; c++)
            if (d[s][c] < lval) { lval = d[s][c]; lidx = (s << 3) | c; }

    for (int sel = 0; sel < KSIM; sel++) {
        float rv = lval;
        int   ri = ((tid + ((lidx >> 3) << 8)) << 3) | (lidx & 7);  // task*8+c
#pragma unroll
        for (int off = 32; off > 0; off >>= 1) {
            float ov = __shfl_down(rv, off);
            int   oi = __shfl_down(ri, off);
            if (ov < rv) { rv = ov; ri = oi; }
        }
        if ((tid & 63) == 0) { swv[tid >> 6] = rv; swi[tid >> 6] = ri; }
        __syncthreads();
        float bval = swv[0]; int bidx = swi[0];
#pragma unroll
        for (int w2 = 1; w2 < 4; w2++)
            if (swv[w2] < bval) { bval = swv[w2]; bidx = swi[w2]; }
        if (tid == 0) {
            int task2 = bidx >> 3;
            int drx = task2 % WINW;
            int dcx = (task2 / WINW) * 8 + (bidx & 7);
            inds[blk * KSIM + sel] =
                (hr + drx - VRAD) * NPOS + (wr + dcx - VRAD);
        }
        __syncthreads();
        int otid = (bidx >> 3) & 255;
        if (tid == otid) {
            int code = (((bidx >> 3) >> 8) << 3) | (bidx & 7);
            lval = INFD; lidx = 0;
#pragma unroll
            for (int s = 0; s < 3; s++)
#pragma unroll
                for (int c = 0; c < 8; c++) {
                    if (((s << 3) | c) == code) d[s][c] = INFD;
                    if (d[s][c] < lval) { lval = d[s][c]; lidx = (s << 3) | c; }
                }
        }
    }
}

// ---------------------------------------------------------------------------
// Stage 2+3: tiled denoise. LDS-read-count reduction: 2x2-blocked Q build
// (121 reads/entry vs 242) and 2r-blocked xhat with A rows + patch bases
// hoisted to registers (~85 VGPR, no spill at (512,1)).
// ---------------------------------------------------------------------------
__global__ __launch_bounds__(512, 1)
void dn_kernel(const float* __restrict__ y, const int* __restrict__ inds,
               float2* __restrict__ nd, int R)
{
    __shared__ float  src[FOOT][SPITCH];     // 29.6 KB
    __shared__ float2 accH[42][FPITCH];      // 28.6 KB
    __shared__ float  Qm[16][16][17];        // 17.4 KB (Q -> Qinv -> theta -> A)
    __shared__ float  s1[16][16];
    __shared__ float  s2[16];
    __shared__ float  wl[16][16];
    __shared__ short  pr_[16][16], pc_[16][16];

    const int blk = blockIdx.x;
    const int n  = blk / 100;
    const int tr = blk % 100;
    const int ti = tr / 10, tj = tr % 10;
    const int r0 = 12 * ti - VRAD, c0 = 12 * tj - VRAD;
    const int tid = threadIdx.x;
    const float* img = y + n * HH * WW;
    const float* sfl = &src[0][0];

    if (tid < 256) {
        int g = tid >> 4, m = tid & 15;
        int gg = n * (HREF * WREF) + (ti * 4 + (g >> 2)) * WREF + (tj * 4 + (g & 3));
        int idx = inds[gg * KSIM + m];
        pr_[g][m] = (short)(idx / NPOS);
        pc_[g][m] = (short)(idx % NPOS);
    }
    for (int t = tid; t < FOOT * FOOT; t += 512) {
        int rr = t / FOOT, cc = t % FOOT;
        int gr = r0 + rr, gc = c0 + cc;
        float vv = 0.f;
        if (gr >= 0 && gr < HH && gc >= 0 && gc < WW) vv = img[gr * WW + gc];
        src[rr][cc] = vv;
    }
    __syncthreads();

    // ---- Q: 2x2-blocked, 16 g x 36 pair-tasks = 576 ----
    for (int k = 0; k < 2; k++) {
        int t2 = tid + k * 512;
        if (t2 < 16 * 36) {
            int g = t2 / 36, e = t2 % 36;
            int ip = (int)((17.f - sqrtf(289.f - 8.f * (float)e)) * 0.5f + 1e-4f);
            int jp = ip + e - (17 - ip) * ip / 2;
            int i0 = ip * 2, j0 = jp * 2;
            int bi0 = ((int)pr_[g][i0]     - r0) * SPITCH + ((int)pc_[g][i0]     - c0);
            int bi1 = ((int)pr_[g][i0 + 1] - r0) * SPITCH + ((int)pc_[g][i0 + 1] - c0);
            int bj0 = ((int)pr_[g][j0]     - r0) * SPITCH + ((int)pc_[g][j0]     - c0);
            int bj1 = ((int)pr_[g][j0 + 1] - r0) * SPITCH + ((int)pc_[g][j0 + 1] - c0);
            float s00 = 0.f, s01 = 0.f, s10 = 0.f, s11 = 0.f;
            for (int a = 0; a < PP; a++) {
                const float* Ri0 = sfl + bi0 + a * SPITCH;
                const float* Ri1 = sfl + bi1 + a * SPITCH;
                const float* Rj0 = sfl + bj0 + a * SPITCH;
                const float* Rj1 = sfl + bj1 + a * SPITCH;
#pragma unroll
                for (int b = 0; b < PP; b++) {
                    float x0 = Ri0[b], x1 = Ri1[b];
                    float y0 = Rj0[b], y1 = Rj1[b];
                    s00 += x0 * y0; s01 += x0 * y1;
                    s10 += x1 * y0; s11 += x1 * y1;
                }
            }
            float de = (ip == jp) ? EPS_E : 0.f;
            Qm[g][i0][j0] = s00 + de;         Qm[g][j0][i0] = s00 + de;
            Qm[g][i0][j0 + 1] = s01;          Qm[g][j0 + 1][i0] = s01;
            Qm[g][i0 + 1][j0] = s10;          Qm[g][j0][i0 + 1] = s10;
            Qm[g][i0 + 1][j0 + 1] = s11 + de; Qm[g][j0 + 1][i0 + 1] = s11 + de;
        }
    }
    __syncthreads();

    // ---- lockstep Gauss-Jordan inversion (16 SPD matrices) ----
    const int uu = tid >> 8, ii = (tid >> 4) & 15, jj = tid & 15;
    for (int ks = 0; ks < 16; ks++) {
        float fA[8], rk[8], pv[8], aij[8];
#pragma unroll
        for (int k = 0; k < 8; k++) {
            int g = uu + 2 * k;
            fA[k]  = Qm[g][ii][ks];
            rk[k]  = Qm[g][ks][jj];
            pv[k]  = Qm[g][ks][ks];
            aij[k] = Qm[g][ii][jj];
        }
        __syncthreads();
#pragma unroll
        for (int k = 0; k < 8; k++) {
            int g = uu + 2 * k;
            float inv = 1.f / pv[k];
            float nv;
            if (ii == ks) nv = (jj == ks) ? inv : rk[k] * inv;
            else          nv = (jj == ks) ? -fA[k] * inv : aij[k] - fA[k] * rk[k] * inv;
            Qm[g][ii][jj] = nv;
        }
        __syncthreads();
    }

    // ---- s1, s2, theta (in-place), weights, fold w into theta ----
    if (tid < 256) {
        int g = tid >> 4, a = tid & 15;
        float s = 0.f;
#pragma unroll
        for (int b2 = 0; b2 < 16; b2++) s += Qm[g][a][b2];
        s1[g][a] = s;
    }
    __syncthreads();
    if (tid < 16) {
        float s = 0.f;
#pragma unroll
        for (int a = 0; a < 16; a++) s += s1[tid][a];
        s2[tid] = s;
    }
    __syncthreads();
#pragma unroll
    for (int k = 0; k < 8; k++) {
        int g = uu + 2 * k;
        float t = ((ii == jj) ? 1.f : 0.f)
                - (Qm[g][ii][jj] - s1[g][ii] * s1[g][jj] / s2[g]) * DE_C;
        Qm[g][ii][jj] = t;
    }
    __syncthreads();
    if (tid < 256) {
        int g = tid >> 4, r = tid & 15;
        float s = 0.f;
#pragma unroll
        for (int m2 = 0; m2 < 16; m2++) { float t = Qm[g][m2][r]; s += t * t; }
        s = fminf(fmaxf(s, 1.f / 16.f), 1.f);
        wl[g][r] = 1.f / s;
    }
    __syncthreads();
#pragma unroll
    for (int k = 0; k < 8; k++) {            // A[m][r] = theta[m][r] * w[r]
        int g = uu + 2 * k;
        Qm[g][ii][jj] *= wl[g][jj];
    }
    __syncthreads();

    // ---- hoist per-thread xhat state: thread = (g, rq in 8, pq in 4) ----
    const int g6 = tid >> 5;
    const int sub = tid & 31;
    const int rq = sub >> 2;        // r = rq*2 + k
    const int pq = sub & 3;         // px = pq*31 + t, t<31
    int bs[16];
#pragma unroll
    for (int m = 0; m < 16; m++)
        bs[m] = ((int)pr_[g6][m] - r0) * SPITCH + ((int)pc_[g6][m] - c0);
    float Ar[2][16]; float wr2[2]; int ar2[2], ac2[2];
#pragma unroll
    for (int k = 0; k < 2; k++) {
        int r = rq * 2 + k;
#pragma unroll
        for (int m = 0; m < 16; m++) Ar[k][m] = Qm[g6][m][r];
        wr2[k] = wl[g6][r];
        ar2[k] = (int)pr_[g6][r] - r0;
        ac2[k] = (int)pc_[g6][r] - c0;
    }

    // ---- two half-passes: blocked xhat + LDS scatter + flush ----
    float2* ndI = nd + ((size_t)(blk & (R - 1)) * NIMG + n) * HH * WW;
#pragma unroll 1
    for (int half = 0; half < 2; half++) {
        const int h0 = half * 42;
        for (int t = tid; t < 42 * FPITCH; t += 512)
            ((float2*)accH)[t] = make_float2(0.f, 0.f);
        __syncthreads();

#pragma unroll 1
        for (int t = 0; t < 31; t++) {
            int px = pq * 31 + t;
            if (px < 121) {
                int dra = px / 11, dca = px % 11;
                int hA0 = ar2[0] + dra, hA1 = ar2[1] + dra;
                bool p0 = (hA0 >= h0 && hA0 < h0 + 42);
                bool p1 = (hA1 >= h0 && hA1 < h0 + 42);
                if (p0 || p1) {
                    const int off = dra * SPITCH + dca;
                    float yv[16];
#pragma unroll
                    for (int m = 0; m < 16; m++) yv[m] = sfl[bs[m] + off];
                    if (p0) {
                        float xw = 0.f;
#pragma unroll
                        for (int m = 0; m < 16; m++) xw += Ar[0][m] * yv[m];
                        float* cell = (float*)&accH[hA0 - h0][ac2[0] + dca];
                        __hip_atomic_fetch_add(cell,     xw,
                            __ATOMIC_RELAXED, __HIP_MEMORY_SCOPE_WORKGROUP);
                        __hip_atomic_fetch_add(cell + 1, wr2[0],
                            __ATOMIC_RELAXED, __HIP_MEMORY_SCOPE_WORKGROUP);
                    }
                    if (p1) {
                        float xw = 0.f;
#pragma unroll
                        for (int m = 0; m < 16; m++) xw += Ar[1][m] * yv[m];
                        float* cell = (float*)&accH[hA1 - h0][ac2[1] + dca];
                        __hip_atomic_fetch_add(cell,     xw,
                            __ATOMIC_RELAXED, __HIP_MEMORY_SCOPE_WORKGROUP);
                        __hip_atomic_fetch_add(cell + 1, wr2[1],
                            __ATOMIC_RELAXED, __HIP_MEMORY_SCOPE_WORKGROUP);
                    }
                }
            }
        }
        __syncthreads();

        for (int t = tid; t < 42 * FOOT; t += 512) {
            int rr = t / FOOT, cc = t % FOOT;
            float2 vv = accH[rr][cc];
            if (vv.y != 0.f) {
                int px = (r0 + h0 + rr) * WW + (c0 + cc);
#if defined(__has_builtin) && __has_builtin(__builtin_amdgcn_global_atomic_fadd_v2f32)
                typedef float v2f __attribute__((ext_vector_type(2)));
                __builtin_amdgcn_global_atomic_fadd_v2f32((v2f*)&ndI[px], (v2f){vv.x, vv.y});
#else
                atomicAdd(&ndI[px].x, vv.x);
                atomicAdd(&ndI[px].y, vv.y);
#endif
            }
        }
        __syncthreads();
    }
}

// ---------------------------------------------------------------------------
// Stage 4: out = sum_r num_r / sum_r den_r
// ---------------------------------------------------------------------------
__global__ __launch_bounds__(256)
void fin_kernel(const float2* __restrict__ nd, float* __restrict__ out, int R)
{
    int t = blockIdx.x * 256 + threadIdx.x;
    if (t < NIMG * HH * WW) {
        float sn = 0.f, sd = 0.f;
        for (int r = 0; r < R; r++) {
            float2 vv = nd[(size_t)r * NIMG * HH * WW + t];
            sn += vv.x; sd += vv.y;
        }
        out[t] = sn / sd;
    }
}

extern "C" void kernel_launch(void* const* d_in, const int* in_sizes, int n_in,
                              void* d_out, int out_size, void* d_ws, size_t ws_size,
                              hipStream_t stream)
{
    const float* y = (const float*)d_in[0];
    float* out = (float*)d_out;

    size_t perRep = (size_t)NIMG * HH * WW * sizeof(float2);   // 524288
    size_t indsB  = (size_t)NGROUP * KSIM * sizeof(int);       // 409600
    size_t cnormB = (size_t)NIMG * NPOS * CNP * sizeof(float); // 226560
    int R = 1;
    while (R < 4 && perRep * (size_t)(R * 2) + indsB + cnormB <= ws_size) R <<= 1;

    float2* nd    = (float2*)d_ws;
    int*    inds  = (int*)((char*)d_ws + perRep * (size_t)R);
    float*  cnorm = (float*)((char*)inds + indsB);

    hipMemsetAsync(nd, 0, perRep * (size_t)R, stream);
    bm_norm<<<NIMG * NPOS, 128, 0, stream>>>(y, cnorm);
    bm_kernel<<<NGROUP, 256, 0, stream>>>(y, cnorm, inds);
    dn_kernel<<<NIMG * 100, 512, 0, stream>>>(y, inds, nd, R);
    fin_kernel<<<(NIMG * HH * WW + 255) / 256, 256, 0, stream>>>(nd, out, R);
}

// Round 10
// 461.283 us; speedup vs baseline: 22.2502x; 22.2502x over previous
//
#include <hip/hip_runtime.h>
#include <math.h>

#define HH 128
#define WW 128
#define NIMG 4
#define PP 11
#define KSIM 16
#define STRIDE_S 3
#define VRAD 32
#define WINW 65             // 2V+1
#define NTASK (WINW*9)      // 585 tasks: (8-wide dc strip, drx)
#define HREF 40
#define WREF 40
#define NPOS 118            // H-P+1
#define WROWS 75            // 2V+P
#define WPITCH 84
#define NGROUP (NIMG*HREF*WREF) // 6400
#define EPS_E 30.25f        // n*alpha^2*sigma^2
#define DE_C 151.25f        // D+E
#define INFD 3.0e38f
#define RTASK 292           // c0=32, drx=32: the (0,0)-displacement candidate

#define FOOT 84
#define FPITCH 85
#define SPITCH 88

// ---------------------------------------------------------------------------
// Stage 1: block matching — EXACT R8 version (proven ~202us, no spill).
// dist = |c|^2 - 2<c,r>; colsq from registers; block-wide top-16 selection.
// ---------------------------------------------------------------------------
__global__ __launch_bounds__(256, 5)
void bm_kernel(const float* __restrict__ y, int* __restrict__ inds)
{
    __shared__ float win[WROWS][WPITCH];   // 25.2 KB
    __shared__ float swv[4];
    __shared__ int   swi[4];

    const int blk = blockIdx.x;
    const int n   = blk / (HREF*WREF);
    const int rem = blk % (HREF*WREF);
    const int hr  = (rem / WREF) * STRIDE_S;
    const int wr  = (rem % WREF) * STRIDE_S;
    const float* img = y + n * HH * WW;
    const int tid = threadIdx.x;

    for (int t = tid; t < WROWS * WPITCH; t += 256) {
        int r = t / WPITCH, c = t % WPITCH;
        int gr = hr - VRAD + r, gc = wr - VRAD + c;
        float v = 0.f;
        if (c < WROWS && gr >= 0 && gr < HH && gc >= 0 && gc < WW)
            v = img[gr * WW + gc];
        win[r][c] = v;
    }
    __syncthreads();

    float d[3][8];
#pragma unroll
    for (int s = 0; s < 3; s++)
#pragma unroll
        for (int c = 0; c < 8; c++) d[s][c] = INFD;

#pragma unroll
    for (int s = 0; s < 3; s++) {
        int task = tid + (s << 8);
        if (task < NTASK) {
            // remapped: consecutive lanes -> consecutive drx (same dc-chunk)
            int drx = task % WINW;
            int c0  = (task / WINW) * 8;
            int rr  = hr + drx - VRAD;
            bool rowok = (rr >= 0 && rr <= HH - PP);
            if (rowok) {
                float dot[8];
                float colsq[18];
#pragma unroll
                for (int c = 0; c < 8; c++) dot[c] = 0.f;
#pragma unroll
                for (int j2 = 0; j2 < 18; j2++) colsq[j2] = 0.f;
                for (int a = 0; a < PP; a++) {
                    const float4* w4 = reinterpret_cast<const float4*>(&win[drx + a][c0]);
                    float4 A0 = w4[0], A1 = w4[1], A2 = w4[2], A3 = w4[3];
                    float2 A4 = *reinterpret_cast<const float2*>(&win[drx + a][c0 + 16]);
                    float wv[18] = {A0.x,A0.y,A0.z,A0.w, A1.x,A1.y,A1.z,A1.w,
                                    A2.x,A2.y,A2.z,A2.w, A3.x,A3.y,A3.z,A3.w,
                                    A4.x,A4.y};
                    const float4* r4 = reinterpret_cast<const float4*>(&win[VRAD + a][VRAD]);
                    float4 R0 = r4[0], R1 = r4[1];
                    float2 R2 = *reinterpret_cast<const float2*>(&win[VRAD + a][VRAD + 8]);
                    float  R3 = win[VRAD + a][VRAD + 10];
                    float rv[11] = {R0.x,R0.y,R0.z,R0.w, R1.x,R1.y,R1.z,R1.w,
                                    R2.x,R2.y, R3};
#pragma unroll
                    for (int j2 = 0; j2 < 18; j2++) colsq[j2] += wv[j2] * wv[j2];
#pragma unroll
                    for (int b = 0; b < PP; b++) {
#pragma unroll
                        for (int c = 0; c < 8; c++)
                            dot[c] += wv[b + c] * rv[b];
                    }
                }
#pragma unroll
                for (int j2 = 1; j2 < 18; j2++) colsq[j2] += colsq[j2 - 1];
#pragma unroll
                for (int c = 0; c < 8; c++) {
                    int dcx = c0 + c;
                    int cc  = wr + dcx - VRAD;
                    float norm = colsq[c + 10] - (c ? colsq[c - 1] : 0.f);
                    if (dcx < WINW && cc >= 0 && cc <= WW - PP)
                        d[s][c] = norm - 2.f * dot[c];
                }
            }
            if (task == RTASK) d[s][0] = -INFD;   // reference always kept
        }
    }

    float lval = INFD; int lidx = 0;
#pragma unroll
    for (int s = 0; s < 3; s++)
#pragma unroll
        for (int c = 0; c < 8; c++)
            if (d[s][c] < lval) { lval = d[s][c]; lidx = (s << 3) | c; }

    for (int sel = 0; sel < KSIM; sel++) {
        float rv = lval;
        int   ri = ((tid + ((lidx >> 3) << 8)) << 3) | (lidx & 7);  // task*8+c
#pragma unroll
        for (int off = 32; off > 0; off >>= 1) {
            float ov = __shfl_down(rv, off);
            int   oi = __shfl_down(ri, off);
            if (ov < rv) { rv = ov; ri = oi; }
        }
        if ((tid & 63) == 0) { swv[tid >> 6] = rv; swi[tid >> 6] = ri; }
        __syncthreads();
        float bval = swv[0]; int bidx = swi[0];
#pragma unroll
        for (int w2 = 1; w2 < 4; w2++)
            if (swv[w2] < bval) { bval = swv[w2]; bidx = swi[w2]; }
        if (tid == 0) {
            int task2 = bidx >> 3;
            int drx = task2 % WINW;
            int dcx = (task2 / WINW) * 8 + (bidx & 7);
            inds[blk * KSIM + sel] =
                (hr + drx - VRAD) * NPOS + (wr + dcx - VRAD);
        }
        __syncthreads();
        int otid = (bidx >> 3) & 255;
        if (tid == otid) {
            int code = (((bidx >> 3) >> 8) << 3) | (bidx & 7);
            lval = INFD; lidx = 0;
#pragma unroll
            for (int s = 0; s < 3; s++)
#pragma unroll
                for (int c = 0; c < 8; c++) {
                    if (((s << 3) | c) == code) d[s][c] = INFD;
                    if (d[s][c] < lval) { lval = d[s][c]; lidx = (s << 3) | c; }
                }
        }
    }
}

// ---------------------------------------------------------------------------
// Stage 2+3: tiled denoise — EXACT R9 version (proven ~180us).
// 2x2-blocked Q build, lockstep GJ, 2r-blocked xhat with hoisted A/bases.
// ---------------------------------------------------------------------------
__global__ __launch_bounds__(512, 1)
void dn_kernel(const float* __restrict__ y, const int* __restrict__ inds,
               float2* __restrict__ nd, int R)
{
    __shared__ float  src[FOOT][SPITCH];     // 29.6 KB
    __shared__ float2 accH[42][FPITCH];      // 28.6 KB
    __shared__ float  Qm[16][16][17];        // 17.4 KB (Q -> Qinv -> theta -> A)
    __shared__ float  s1[16][16];
    __shared__ float  s2[16];
    __shared__ float  wl[16][16];
    __shared__ short  pr_[16][16], pc_[16][16];

    const int blk = blockIdx.x;
    const int n  = blk / 100;
    const int tr = blk % 100;
    const int ti = tr / 10, tj = tr % 10;
    const int r0 = 12 * ti - VRAD, c0 = 12 * tj - VRAD;
    const int tid = threadIdx.x;
    const float* img = y + n * HH * WW;
    const float* sfl = &src[0][0];

    if (tid < 256) {
        int g = tid >> 4, m = tid & 15;
        int gg = n * (HREF * WREF) + (ti * 4 + (g >> 2)) * WREF + (tj * 4 + (g & 3));
        int idx = inds[gg * KSIM + m];
        pr_[g][m] = (short)(idx / NPOS);
        pc_[g][m] = (short)(idx % NPOS);
    }
    for (int t = tid; t < FOOT * FOOT; t += 512) {
        int rr = t / FOOT, cc = t % FOOT;
        int gr = r0 + rr, gc = c0 + cc;
        float vv = 0.f;
        if (gr >= 0 && gr < HH && gc >= 0 && gc < WW) vv = img[gr * WW + gc];
        src[rr][cc] = vv;
    }
    __syncthreads();

    // ---- Q: 2x2-blocked, 16 g x 36 pair-tasks = 576 ----
    for (int k = 0; k < 2; k++) {
        int t2 = tid + k * 512;
        if (t2 < 16 * 36) {
            int g = t2 / 36, e = t2 % 36;
            int ip = (int)((17.f - sqrtf(289.f - 8.f * (float)e)) * 0.5f + 1e-4f);
            int jp = ip + e - (17 - ip) * ip / 2;
            int i0 = ip * 2, j0 = jp * 2;
            int bi0 = ((int)pr_[g][i0]     - r0) * SPITCH + ((int)pc_[g][i0]     - c0);
            int bi1 = ((int)pr_[g][i0 + 1] - r0) * SPITCH + ((int)pc_[g][i0 + 1] - c0);
            int bj0 = ((int)pr_[g][j0]     - r0) * SPITCH + ((int)pc_[g][j0]     - c0);
            int bj1 = ((int)pr_[g][j0 + 1] - r0) * SPITCH + ((int)pc_[g][j0 + 1] - c0);
            float s00 = 0.f, s01 = 0.f, s10 = 0.f, s11 = 0.f;
            for (int a = 0; a < PP; a++) {
                const float* Ri0 = sfl + bi0 + a * SPITCH;
                const float* Ri1 = sfl + bi1 + a * SPITCH;
                const float* Rj0 = sfl + bj0 + a * SPITCH;
                const float* Rj1 = sfl + bj1 + a * SPITCH;
#pragma unroll
                for (int b = 0; b < PP; b++) {
                    float x0 = Ri0[b], x1 = Ri1[b];
                    float y0 = Rj0[b], y1 = Rj1[b];
                    s00 += x0 * y0; s01 += x0 * y1;
                    s10 += x1 * y0; s11 += x1 * y1;
                }
            }
            float de = (ip == jp) ? EPS_E : 0.f;
            Qm[g][i0][j0] = s00 + de;         Qm[g][j0][i0] = s00 + de;
            Qm[g][i0][j0 + 1] = s01;          Qm[g][j0 + 1][i0] = s01;
            Qm[g][i0 + 1][j0] = s10;          Qm[g][j0][i0 + 1] = s10;
            Qm[g][i0 + 1][j0 + 1] = s11 + de; Qm[g][j0 + 1][i0 + 1] = s11 + de;
        }
    }
    __syncthreads();

    // ---- lockstep Gauss-Jordan inversion (16 SPD matrices) ----
    const int uu = tid >> 8, ii = (tid >> 4) & 15, jj = tid & 15;
    for (int ks = 0; ks < 16; ks++) {
        float fA[8], rk[8], pv[8], aij[8];
#pragma unroll
        for (int k = 0; k < 8; k++) {
            int g = uu + 2 * k;
            fA[k]  = Qm[g][ii][ks];
            rk[k]  = Qm[g][ks][jj];
            pv[k]  = Qm[g][ks][ks];
            aij[k] = Qm[g][ii][jj];
        }
        __syncthreads();
#pragma unroll
        for (int k = 0; k < 8; k++) {
            int g = uu + 2 * k;
            float inv = 1.f / pv[k];
            float nv;
            if (ii == ks) nv = (jj == ks) ? inv : rk[k] * inv;
            else          nv = (jj == ks) ? -fA[k] * inv : aij[k] - fA[k] * rk[k] * inv;
            Qm[g][ii][jj] = nv;
        }
        __syncthreads();
    }

    // ---- s1, s2, theta (in-place), weights, fold w into theta ----
    if (tid < 256) {
        int g = tid >> 4, a = tid & 15;
        float s = 0.f;
#pragma unroll
        for (int b2 = 0; b2 < 16; b2++) s += Qm[g][a][b2];
        s1[g][a] = s;
    }
    __syncthreads();
    if (tid < 16) {
        float s = 0.f;
#pragma unroll
        for (int a = 0; a < 16; a++) s += s1[tid][a];
        s2[tid] = s;
    }
    __syncthreads();
#pragma unroll
    for (int k = 0; k < 8; k++) {
        int g = uu + 2 * k;
        float t = ((ii == jj) ? 1.f : 0.f)
                - (Qm[g][ii][jj] - s1[g][ii] * s1[g][jj] / s2[g]) * DE_C;
        Qm[g][ii][jj] = t;
    }
    __syncthreads();
    if (tid < 256) {
        int g = tid >> 4, r = tid & 15;
        float s = 0.f;
#pragma unroll
        for (int m2 = 0; m2 < 16; m2++) { float t = Qm[g][m2][r]; s += t * t; }
        s = fminf(fmaxf(s, 1.f / 16.f), 1.f);
        wl[g][r] = 1.f / s;
    }
    __syncthreads();
#pragma unroll
    for (int k = 0; k < 8; k++) {            // A[m][r] = theta[m][r] * w[r]
        int g = uu + 2 * k;
        Qm[g][ii][jj] *= wl[g][jj];
    }
    __syncthreads();

    // ---- hoist per-thread xhat state: thread = (g, rq in 8, pq in 4) ----
    const int g6 = tid >> 5;
    const int sub = tid & 31;
    const int rq = sub >> 2;        // r = rq*2 + k
    const int pq = sub & 3;         // px = pq*31 + t, t<31
    int bs[16];
#pragma unroll
    for (int m = 0; m < 16; m++)
        bs[m] = ((int)pr_[g6][m] - r0) * SPITCH + ((int)pc_[g6][m] - c0);
    float Ar[2][16]; float wr2[2]; int ar2[2], ac2[2];
#pragma unroll
    for (int k = 0; k < 2; k++) {
        int r = rq * 2 + k;
#pragma unroll
        for (int m = 0; m < 16; m++) Ar[k][m] = Qm[g6][m][r];
        wr2[k] = wl[g6][r];
        ar2[k] = (int)pr_[g6][r] - r0;
        ac2[k] = (int)pc_[g6][r] - c0;
    }

    // ---- two half-passes: blocked xhat + LDS scatter + flush ----
    float2* ndI = nd + ((size_t)(blk & (R - 1)) * NIMG + n) * HH * WW;
#pragma unroll 1
    for (int half = 0; half < 2; half++) {
        const int h0 = half * 42;
        for (int t = tid; t < 42 * FPITCH; t += 512)
            ((float2*)accH)[t] = make_float2(0.f, 0.f);
        __syncthreads();

#pragma unroll 1
        for (int t = 0; t < 31; t++) {
            int px = pq * 31 + t;
            if (px < 121) {
                int dra = px / 11, dca = px % 11;
                int hA0 = ar2[0] + dra, hA1 = ar2[1] + dra;
                bool p0 = (hA0 >= h0 && hA0 < h0 + 42);
                bool p1 = (hA1 >= h0 && hA1 < h0 + 42);
                if (p0 || p1) {
                    const int off = dra * SPITCH + dca;
                    float yv[16];
#pragma unroll
                    for (int m = 0; m < 16; m++) yv[m] = sfl[bs[m] + off];
                    if (p0) {
                        float xw = 0.f;
#pragma unroll
                        for (int m = 0; m < 16; m++) xw += Ar[0][m] * yv[m];
                        float* cell = (float*)&accH[hA0 - h0][ac2[0] + dca];
                        __hip_atomic_fetch_add(cell,     xw,
                            __ATOMIC_RELAXED, __HIP_MEMORY_SCOPE_WORKGROUP);
                        __hip_atomic_fetch_add(cell + 1, wr2[0],
                            __ATOMIC_RELAXED, __HIP_MEMORY_SCOPE_WORKGROUP);
                    }
                    if (p1) {
                        float xw = 0.f;
#pragma unroll
                        for (int m = 0; m < 16; m++) xw += Ar[1][m] * yv[m];
                        float* cell = (float*)&accH[hA1 - h0][ac2[1] + dca];
                        __hip_atomic_fetch_add(cell,     xw,
                            __ATOMIC_RELAXED, __HIP_MEMORY_SCOPE_WORKGROUP);
                        __hip_atomic_fetch_add(cell + 1, wr2[1],
                            __ATOMIC_RELAXED, __HIP_MEMORY_SCOPE_WORKGROUP);
                    }
                }
            }
        }
        __syncthreads();

        for (int t = tid; t < 42 * FOOT; t += 512) {
            int rr = t / FOOT, cc = t % FOOT;
            float2 vv = accH[rr][cc];
            if (vv.y != 0.f) {
                int px = (r0 + h0 + rr) * WW + (c0 + cc);
#if defined(__has_builtin) && __has_builtin(__builtin_amdgcn_global_atomic_fadd_v2f32)
                typedef float v2f __attribute__((ext_vector_type(2)));
                __builtin_amdgcn_global_atomic_fadd_v2f32((v2f*)&ndI[px], (v2f){vv.x, vv.y});
#else
                atomicAdd(&ndI[px].x, vv.x);
                atomicAdd(&ndI[px].y, vv.y);
#endif
            }
        }
        __syncthreads();
    }
}

// ---------------------------------------------------------------------------
// Stage 4: out = sum_r num_r / sum_r den_r
// ---------------------------------------------------------------------------
__global__ __launch_bounds__(256)
void fin_kernel(const float2* __restrict__ nd, float* __restrict__ out, int R)
{
    int t = blockIdx.x * 256 + threadIdx.x;
    if (t < NIMG * HH * WW) {
        float sn = 0.f, sd = 0.f;
        for (int r = 0; r < R; r++) {
            float2 vv = nd[(size_t)r * NIMG * HH * WW + t];
            sn += vv.x; sd += vv.y;
        }
        out[t] = sn / sd;
    }
}

extern "C" void kernel_launch(void* const* d_in, const int* in_sizes, int n_in,
                              void* d_out, int out_size, void* d_ws, size_t ws_size,
                              hipStream_t stream)
{
    const float* y = (const float*)d_in[0];
    float* out = (float*)d_out;

    size_t perRep = (size_t)NIMG * HH * WW * sizeof(float2);   // 524288
    size_t indsB  = (size_t)NGROUP * KSIM * sizeof(int);       // 409600
    int R = 1;
    while (R < 4 && perRep * (size_t)(R * 2) + indsB <= ws_size) R <<= 1;

    float2* nd   = (float2*)d_ws;
    int*    inds = (int*)((char*)d_ws + perRep * (size_t)R);

    hipMemsetAsync(nd, 0, perRep * (size_t)R, stream);
    bm_kernel<<<NGROUP, 256, 0, stream>>>(y, inds);
    dn_kernel<<<NIMG * 100, 512, 0, stream>>>(y, inds, nd, R);
    fin_kernel<<<(NIMG * HH * WW + 255) / 256, 256, 0, stream>>>(nd, out, R);
}

// Round 11
// 445.308 us; speedup vs baseline: 23.0484x; 1.0359x over previous
//
#include <hip/hip_runtime.h>
#include <math.h>

#define HH 128
#define WW 128
#define NIMG 4
#define PP 11
#define KSIM 16
#define STRIDE_S 3
#define VRAD 32
#define WINW 65             // 2V+1
#define NTASK (WINW*9)      // 585 tasks: (8-wide dc strip, drx)
#define HREF 40
#define WREF 40
#define NPOS 118            // H-P+1
#define WROWS 75            // 2V+P
#define WPITCH 84
#define NGROUP (NIMG*HREF*WREF) // 6400
#define EPS_E 30.25f        // n*alpha^2*sigma^2
#define DE_C 151.25f        // D+E
#define INFD 3.0e38f
#define RTASK 292           // c0=32, drx=32: the (0,0)-displacement candidate
#define THREC 152           // per-group record: 136 tri theta + 16 weights

// ---------------------------------------------------------------------------
// Stage 1: block matching — EXACT R8/R10 version (proven ~205us, no spill).
// ---------------------------------------------------------------------------
__global__ __launch_bounds__(256, 5)
void bm_kernel(const float* __restrict__ y, int* __restrict__ inds)
{
    __shared__ float win[WROWS][WPITCH];   // 25.2 KB
    __shared__ float swv[4];
    __shared__ int   swi[4];

    const int blk = blockIdx.x;
    const int n   = blk / (HREF*WREF);
    const int rem = blk % (HREF*WREF);
    const int hr  = (rem / WREF) * STRIDE_S;
    const int wr  = (rem % WREF) * STRIDE_S;
    const float* img = y + n * HH * WW;
    const int tid = threadIdx.x;

    for (int t = tid; t < WROWS * WPITCH; t += 256) {
        int r = t / WPITCH, c = t % WPITCH;
        int gr = hr - VRAD + r, gc = wr - VRAD + c;
        float v = 0.f;
        if (c < WROWS && gr >= 0 && gr < HH && gc >= 0 && gc < WW)
            v = img[gr * WW + gc];
        win[r][c] = v;
    }
    __syncthreads();

    float d[3][8];
#pragma unroll
    for (int s = 0; s < 3; s++)
#pragma unroll
        for (int c = 0; c < 8; c++) d[s][c] = INFD;

#pragma unroll
    for (int s = 0; s < 3; s++) {
        int task = tid + (s << 8);
        if (task < NTASK) {
            int drx = task % WINW;
            int c0  = (task / WINW) * 8;
            int rr  = hr + drx - VRAD;
            bool rowok = (rr >= 0 && rr <= HH - PP);
            if (rowok) {
                float dot[8];
                float colsq[18];
#pragma unroll
                for (int c = 0; c < 8; c++) dot[c] = 0.f;
#pragma unroll
                for (int j2 = 0; j2 < 18; j2++) colsq[j2] = 0.f;
                for (int a = 0; a < PP; a++) {
                    const float4* w4 = reinterpret_cast<const float4*>(&win[drx + a][c0]);
                    float4 A0 = w4[0], A1 = w4[1], A2 = w4[2], A3 = w4[3];
                    float2 A4 = *reinterpret_cast<const float2*>(&win[drx + a][c0 + 16]);
                    float wv[18] = {A0.x,A0.y,A0.z,A0.w, A1.x,A1.y,A1.z,A1.w,
                                    A2.x,A2.y,A2.z,A2.w, A3.x,A3.y,A3.z,A3.w,
                                    A4.x,A4.y};
                    const float4* r4 = reinterpret_cast<const float4*>(&win[VRAD + a][VRAD]);
                    float4 R0 = r4[0], R1 = r4[1];
                    float2 R2 = *reinterpret_cast<const float2*>(&win[VRAD + a][VRAD + 8]);
                    float  R3 = win[VRAD + a][VRAD + 10];
                    float rv[11] = {R0.x,R0.y,R0.z,R0.w, R1.x,R1.y,R1.z,R1.w,
                                    R2.x,R2.y, R3};
#pragma unroll
                    for (int j2 = 0; j2 < 18; j2++) colsq[j2] += wv[j2] * wv[j2];
#pragma unroll
                    for (int b = 0; b < PP; b++) {
#pragma unroll
                        for (int c = 0; c < 8; c++)
                            dot[c] += wv[b + c] * rv[b];
                    }
                }
#pragma unroll
                for (int j2 = 1; j2 < 18; j2++) colsq[j2] += colsq[j2 - 1];
#pragma unroll
                for (int c = 0; c < 8; c++) {
                    int dcx = c0 + c;
                    int cc  = wr + dcx - VRAD;
                    float norm = colsq[c + 10] - (c ? colsq[c - 1] : 0.f);
                    if (dcx < WINW && cc >= 0 && cc <= WW - PP)
                        d[s][c] = norm - 2.f * dot[c];
                }
            }
            if (task == RTASK) d[s][0] = -INFD;
        }
    }

    float lval = INFD; int lidx = 0;
#pragma unroll
    for (int s = 0; s < 3; s++)
#pragma unroll
        for (int c = 0; c < 8; c++)
            if (d[s][c] < lval) { lval = d[s][c]; lidx = (s << 3) | c; }

    for (int sel = 0; sel < KSIM; sel++) {
        float rv = lval;
        int   ri = ((tid + ((lidx >> 3) << 8)) << 3) | (lidx & 7);
#pragma unroll
        for (int off = 32; off > 0; off >>= 1) {
            float ov = __shfl_down(rv, off);
            int   oi = __shfl_down(ri, off);
            if (ov < rv) { rv = ov; ri = oi; }
        }
        if ((tid & 63) == 0) { swv[tid >> 6] = rv; swi[tid >> 6] = ri; }
        __syncthreads();
        float bval = swv[0]; int bidx = swi[0];
#pragma unroll
        for (int w2 = 1; w2 < 4; w2++)
            if (swv[w2] < bval) { bval = swv[w2]; bidx = swi[w2]; }
        if (tid == 0) {
            int task2 = bidx >> 3;
            int drx = task2 % WINW;
            int dcx = (task2 / WINW) * 8 + (bidx & 7);
            inds[blk * KSIM + sel] =
                (hr + drx - VRAD) * NPOS + (wr + dcx - VRAD);
        }
        __syncthreads();
        int otid = (bidx >> 3) & 255;
        if (tid == otid) {
            int code = (((bidx >> 3) >> 8) << 3) | (bidx & 7);
            lval = INFD; lidx = 0;
#pragma unroll
            for (int s = 0; s < 3; s++)
#pragma unroll
                for (int c = 0; c < 8; c++) {
                    if (((s << 3) | c) == code) d[s][c] = INFD;
                    if (d[s][c] < lval) { lval = d[s][c]; lidx = (s << 3) | c; }
                }
        }
    }
}

// ---------------------------------------------------------------------------
// Stage 2a: per-group solve (Q, Gauss-Jordan inverse, theta, weights).
// 4 groups per 256-thread block, 4.5 KB LDS -> ~8 blocks/CU: GJ barriers
// overlap across resident blocks. Writes tri-theta(136)+w(16) per group.
// ---------------------------------------------------------------------------
__global__ __launch_bounds__(256)
void dn_solve(const float* __restrict__ y, const int* __restrict__ inds,
              float* __restrict__ thW)
{
    __shared__ float Qs[4][16][17];
    __shared__ float s1[4][16];
    __shared__ float s2[4];
    __shared__ float wl[4][16];
    __shared__ short pr_[4][16], pc_[4][16];

    const int blk = blockIdx.x;          // 1600 blocks
    const int tid = threadIdx.x;
    const int g0 = blk * 4;

    if (tid < 64) {
        int gq = tid >> 4, m = tid & 15;
        int idx = inds[(g0 + gq) * KSIM + m];
        pr_[gq][m] = (short)(idx / NPOS);
        pc_[gq][m] = (short)(idx % NPOS);
    }
    __syncthreads();

    // Q build: 4*136 tasks, patch reads from global (L1-resident)
    for (int t = tid; t < 4 * 136; t += 256) {
        int gq = t / 136, e = t % 136;
        int i = (int)((sqrtf(8.f * (float)e + 1.f) - 1.f) * 0.5f + 1e-4f);
        int j = e - i * (i + 1) / 2;
        const float* img = y + ((g0 + gq) / (HREF * WREF)) * HH * WW;
        const float* Pi = img + (int)pr_[gq][i] * WW + (int)pc_[gq][i];
        const float* Pj = img + (int)pr_[gq][j] * WW + (int)pc_[gq][j];
        float s = (i == j) ? EPS_E : 0.f;
        for (int a = 0; a < PP; a++) {
            const float* Ri = Pi + a * WW;
            const float* Rj = Pj + a * WW;
#pragma unroll
            for (int b = 0; b < PP; b++) s += Ri[b] * Rj[b];
        }
        Qs[gq][i][j] = s;
        Qs[gq][j][i] = s;
    }
    __syncthreads();

    // lockstep Gauss-Jordan: thread = (gq, ii, 4-entry j strip)
    const int gq = tid >> 6, ii = (tid >> 2) & 15, jq = tid & 3;
    for (int ks = 0; ks < 16; ks++) {
        float fA = Qs[gq][ii][ks];
        float pv = Qs[gq][ks][ks];
        float rk[4], aij[4];
#pragma unroll
        for (int q = 0; q < 4; q++) {
            rk[q]  = Qs[gq][ks][jq * 4 + q];
            aij[q] = Qs[gq][ii][jq * 4 + q];
        }
        __syncthreads();
        float inv = 1.f / pv;
#pragma unroll
        for (int q = 0; q < 4; q++) {
            int jj = jq * 4 + q;
            float nv;
            if (ii == ks) nv = (jj == ks) ? inv : rk[q] * inv;
            else          nv = (jj == ks) ? -fA * inv : aij[q] - fA * rk[q] * inv;
            Qs[gq][ii][jj] = nv;
        }
        __syncthreads();
    }

    if (jq == 0) {
        float s = 0.f;
#pragma unroll
        for (int b = 0; b < 16; b++) s += Qs[gq][ii][b];
        s1[gq][ii] = s;
    }
    __syncthreads();
    if (ii == 0 && jq == 0) {
        float s = 0.f;
#pragma unroll
        for (int a = 0; a < 16; a++) s += s1[gq][a];
        s2[gq] = s;
    }
    __syncthreads();
    {   // theta in place (each thread owns its 4 entries: no hazard)
        float s1i = s1[gq][ii];
#pragma unroll
        for (int q = 0; q < 4; q++) {
            int jj = jq * 4 + q;
            float t2 = ((ii == jj) ? 1.f : 0.f)
                     - (Qs[gq][ii][jj] - s1i * s1[gq][jj] / s2[gq]) * DE_C;
            Qs[gq][ii][jj] = t2;
        }
    }
    __syncthreads();
    if (jq == 1) {   // w[r=ii] = 1/clip(sum_m theta[m][r]^2)
        float s = 0.f;
#pragma unroll
        for (int m = 0; m < 16; m++) { float t2 = Qs[gq][m][ii]; s += t2 * t2; }
        s = fminf(fmaxf(s, 1.f / 16.f), 1.f);
        wl[gq][ii] = 1.f / s;
    }
    __syncthreads();

    for (int t = tid; t < 4 * THREC; t += 256) {
        int gg = t / THREC, e = t % THREC;
        float v;
        if (e < 136) {
            int i = (int)((sqrtf(8.f * (float)e + 1.f) - 1.f) * 0.5f + 1e-4f);
            int j = e - i * (i + 1) / 2;
            v = Qs[gg][i][j];          // theta symmetric -> triangular store
        } else {
            v = wl[gg][e - 136];
        }
        thW[(size_t)(g0 + gg) * THREC + e] = v;
    }
}

// ---------------------------------------------------------------------------
// Stage 2b: tiled scatter. Single full-footprint pass, ~3 barriers.
// LDS = full acc (57.1K) + theta stage (9.7K) -> 2 blocks/CU. yv from
// global (L1/L2). Register layout identical to R10's proven xhat (76 VGPR).
// ---------------------------------------------------------------------------
__global__ __launch_bounds__(512, 1)
void dn_scatter(const float* __restrict__ y, const int* __restrict__ inds,
                const float* __restrict__ thW, float2* __restrict__ nd, int R)
{
    __shared__ float2 acc[84][85];        // 57.1 KB
    __shared__ float  thS[16][THREC];     // 9.7 KB
    __shared__ short  pr_[16][16], pc_[16][16];

    const int blk = blockIdx.x;
    const int n  = blk / 100;
    const int tr = blk % 100;
    const int ti = tr / 10, tj = tr % 10;
    const int r0 = 12 * ti - VRAD, c0 = 12 * tj - VRAD;
    const int tid = threadIdx.x;
    const float* img = y + n * HH * WW;

    if (tid < 256) {
        int g = tid >> 4, m = tid & 15;
        int gg = n * (HREF * WREF) + (ti * 4 + (g >> 2)) * WREF + (tj * 4 + (g & 3));
        int idx = inds[gg * KSIM + m];
        pr_[g][m] = (short)(idx / NPOS);
        pc_[g][m] = (short)(idx % NPOS);
    }
    for (int t = tid; t < 16 * THREC; t += 512) {
        int g = t / THREC, e = t % THREC;
        int gg = n * (HREF * WREF) + (ti * 4 + (g >> 2)) * WREF + (tj * 4 + (g & 3));
        thS[g][e] = thW[(size_t)gg * THREC + e];
    }
    for (int t = tid; t < 84 * 85; t += 512)
        ((float2*)acc)[t] = make_float2(0.f, 0.f);
    __syncthreads();

    // thread = (g, rq in 8, pq in 4); r = rq*2+k  (R10-proven register set)
    const int g6 = tid >> 5, sub = tid & 31, rq = sub >> 2, pq = sub & 3;
    int bs[16];
#pragma unroll
    for (int m = 0; m < 16; m++)
        bs[m] = (int)pr_[g6][m] * WW + (int)pc_[g6][m];
    float Ar[2][16]; float wr2[2]; int ar2[2], ac2[2];
#pragma unroll
    for (int k = 0; k < 2; k++) {
        int r = rq * 2 + k;
        float w = thS[g6][136 + r];
#pragma unroll
        for (int m = 0; m < 16; m++) {
            int hi = (m > r) ? m : r, lo = (m > r) ? r : m;
            Ar[k][m] = thS[g6][hi * (hi + 1) / 2 + lo] * w;   // A = theta*w
        }
        wr2[k] = w;
        ar2[k] = (int)pr_[g6][r] - r0;
        ac2[k] = (int)pc_[g6][r] - c0;
    }

#pragma unroll 1
    for (int t = 0; t < 31; t++) {
        int px = pq * 31 + t;
        if (px < 121) {
            int dra = px / 11, dca = px % 11;
            const int off = dra * WW + dca;
            float yv[16];
#pragma unroll
            for (int m = 0; m < 16; m++) yv[m] = img[bs[m] + off];
#pragma unroll
            for (int k = 0; k < 2; k++) {
                float xw = 0.f;
#pragma unroll
                for (int m = 0; m < 16; m++) xw += Ar[k][m] * yv[m];
                float* cell = (float*)&acc[ar2[k] + dra][ac2[k] + dca];
                __hip_atomic_fetch_add(cell,     xw,
                    __ATOMIC_RELAXED, __HIP_MEMORY_SCOPE_WORKGROUP);
                __hip_atomic_fetch_add(cell + 1, wr2[k],
                    __ATOMIC_RELAXED, __HIP_MEMORY_SCOPE_WORKGROUP);
            }
        }
    }
    __syncthreads();

    float2* ndI = nd + ((size_t)(blk & (R - 1)) * NIMG + n) * HH * WW;
    for (int t = tid; t < 84 * 84; t += 512) {
        int rr = t / 84, cc = t % 84;
        float2 vv = acc[rr][cc];
        if (vv.y != 0.f) {
            int px = (r0 + rr) * WW + (c0 + cc);
#if defined(__has_builtin) && __has_builtin(__builtin_amdgcn_global_atomic_fadd_v2f32)
            typedef float v2f __attribute__((ext_vector_type(2)));
            __builtin_amdgcn_global_atomic_fadd_v2f32((v2f*)&ndI[px], (v2f){vv.x, vv.y});
#else
            atomicAdd(&ndI[px].x, vv.x);
            atomicAdd(&ndI[px].y, vv.y);
#endif
        }
    }
}

// ---------------------------------------------------------------------------
// Stage 4: out = sum_r num_r / sum_r den_r
// ---------------------------------------------------------------------------
__global__ __launch_bounds__(256)
void fin_kernel(const float2* __restrict__ nd, float* __restrict__ out, int R)
{
    int t = blockIdx.x * 256 + threadIdx.x;
    if (t < NIMG * HH * WW) {
        float sn = 0.f, sd = 0.f;
        for (int r = 0; r < R; r++) {
            float2 vv = nd[(size_t)r * NIMG * HH * WW + t];
            sn += vv.x; sd += vv.y;
        }
        out[t] = sn / sd;
    }
}

extern "C" void kernel_launch(void* const* d_in, const int* in_sizes, int n_in,
                              void* d_out, int out_size, void* d_ws, size_t ws_size,
                              hipStream_t stream)
{
    const float* y = (const float*)d_in[0];
    float* out = (float*)d_out;

    size_t perRep = (size_t)NIMG * HH * WW * sizeof(float2);   // 524288
    size_t indsB  = (size_t)NGROUP * KSIM * sizeof(int);       // 409600
    size_t thWB   = (size_t)NGROUP * THREC * sizeof(float);    // 3891200
    int R = 1;
    while (R < 4 && perRep * (size_t)(R * 2) + indsB + thWB <= ws_size) R <<= 1;

    float2* nd   = (float2*)d_ws;
    int*    inds = (int*)((char*)d_ws + perRep * (size_t)R);
    float*  thW  = (float*)((char*)inds + indsB);

    hipMemsetAsync(nd, 0, perRep * (size_t)R, stream);
    bm_kernel<<<NGROUP, 256, 0, stream>>>(y, inds);
    dn_solve<<<NGROUP / 4, 256, 0, stream>>>(y, inds, thW);
    dn_scatter<<<NIMG * 100, 512, 0, stream>>>(y, inds, thW, nd, R);
    fin_kernel<<<(NIMG * HH * WW + 255) / 256, 256, 0, stream>>>(nd, out, R);
}

// Round 12
// 427.759 us; speedup vs baseline: 23.9940x; 1.0410x over previous
//
#include <hip/hip_runtime.h>
#include <math.h>

#define HH 128
#define WW 128
#define NIMG 4
#define PP 11
#define KSIM 16
#define STRIDE_S 3
#define VRAD 32
#define WINW 65             // 2V+1
#define NTASK (WINW*9)      // 585 tasks: (8-wide dc strip, drx)
#define HREF 40
#define WREF 40
#define NPOS 118            // H-P+1
#define WROWS 75            // 2V+P
#define WPITCH 84
#define NGROUP (NIMG*HREF*WREF) // 6400
#define EPS_E 30.25f        // n*alpha^2*sigma^2
#define DE_C 151.25f        // D+E
#define INFD 3.0e38f
#define RTASK 292           // c0=32, drx=32: the (0,0)-displacement candidate
#define THREC 152           // per-group record: 136 tri theta + 16 weights

// ---------------------------------------------------------------------------
// Stage 1: block matching — EXACT R8/R10/R11 version (FROZEN, ~233us).
// ---------------------------------------------------------------------------
__global__ __launch_bounds__(256, 5)
void bm_kernel(const float* __restrict__ y, int* __restrict__ inds)
{
    __shared__ float win[WROWS][WPITCH];   // 25.2 KB
    __shared__ float swv[4];
    __shared__ int   swi[4];

    const int blk = blockIdx.x;
    const int n   = blk / (HREF*WREF);
    const int rem = blk % (HREF*WREF);
    const int hr  = (rem / WREF) * STRIDE_S;
    const int wr  = (rem % WREF) * STRIDE_S;
    const float* img = y + n * HH * WW;
    const int tid = threadIdx.x;

    for (int t = tid; t < WROWS * WPITCH; t += 256) {
        int r = t / WPITCH, c = t % WPITCH;
        int gr = hr - VRAD + r, gc = wr - VRAD + c;
        float v = 0.f;
        if (c < WROWS && gr >= 0 && gr < HH && gc >= 0 && gc < WW)
            v = img[gr * WW + gc];
        win[r][c] = v;
    }
    __syncthreads();

    float d[3][8];
#pragma unroll
    for (int s = 0; s < 3; s++)
#pragma unroll
        for (int c = 0; c < 8; c++) d[s][c] = INFD;

#pragma unroll
    for (int s = 0; s < 3; s++) {
        int task = tid + (s << 8);
        if (task < NTASK) {
            int drx = task % WINW;
            int c0  = (task / WINW) * 8;
            int rr  = hr + drx - VRAD;
            bool rowok = (rr >= 0 && rr <= HH - PP);
            if (rowok) {
                float dot[8];
                float colsq[18];
#pragma unroll
                for (int c = 0; c < 8; c++) dot[c] = 0.f;
#pragma unroll
                for (int j2 = 0; j2 < 18; j2++) colsq[j2] = 0.f;
                for (int a = 0; a < PP; a++) {
                    const float4* w4 = reinterpret_cast<const float4*>(&win[drx + a][c0]);
                    float4 A0 = w4[0], A1 = w4[1], A2 = w4[2], A3 = w4[3];
                    float2 A4 = *reinterpret_cast<const float2*>(&win[drx + a][c0 + 16]);
                    float wv[18] = {A0.x,A0.y,A0.z,A0.w, A1.x,A1.y,A1.z,A1.w,
                                    A2.x,A2.y,A2.z,A2.w, A3.x,A3.y,A3.z,A3.w,
                                    A4.x,A4.y};
                    const float4* r4 = reinterpret_cast<const float4*>(&win[VRAD + a][VRAD]);
                    float4 R0 = r4[0], R1 = r4[1];
                    float2 R2 = *reinterpret_cast<const float2*>(&win[VRAD + a][VRAD + 8]);
                    float  R3 = win[VRAD + a][VRAD + 10];
                    float rv[11] = {R0.x,R0.y,R0.z,R0.w, R1.x,R1.y,R1.z,R1.w,
                                    R2.x,R2.y, R3};
#pragma unroll
                    for (int j2 = 0; j2 < 18; j2++) colsq[j2] += wv[j2] * wv[j2];
#pragma unroll
                    for (int b = 0; b < PP; b++) {
#pragma unroll
                        for (int c = 0; c < 8; c++)
                            dot[c] += wv[b + c] * rv[b];
                    }
                }
#pragma unroll
                for (int j2 = 1; j2 < 18; j2++) colsq[j2] += colsq[j2 - 1];
#pragma unroll
                for (int c = 0; c < 8; c++) {
                    int dcx = c0 + c;
                    int cc  = wr + dcx - VRAD;
                    float norm = colsq[c + 10] - (c ? colsq[c - 1] : 0.f);
                    if (dcx < WINW && cc >= 0 && cc <= WW - PP)
                        d[s][c] = norm - 2.f * dot[c];
                }
            }
            if (task == RTASK) d[s][0] = -INFD;
        }
    }

    float lval = INFD; int lidx = 0;
#pragma unroll
    for (int s = 0; s < 3; s++)
#pragma unroll
        for (int c = 0; c < 8; c++)
            if (d[s][c] < lval) { lval = d[s][c]; lidx = (s << 3) | c; }

    for (int sel = 0; sel < KSIM; sel++) {
        float rv = lval;
        int   ri = ((tid + ((lidx >> 3) << 8)) << 3) | (lidx & 7);
#pragma unroll
        for (int off = 32; off > 0; off >>= 1) {
            float ov = __shfl_down(rv, off);
            int   oi = __shfl_down(ri, off);
            if (ov < rv) { rv = ov; ri = oi; }
        }
        if ((tid & 63) == 0) { swv[tid >> 6] = rv; swi[tid >> 6] = ri; }
        __syncthreads();
        float bval = swv[0]; int bidx = swi[0];
#pragma unroll
        for (int w2 = 1; w2 < 4; w2++)
            if (swv[w2] < bval) { bval = swv[w2]; bidx = swi[w2]; }
        if (tid == 0) {
            int task2 = bidx >> 3;
            int drx = task2 % WINW;
            int dcx = (task2 / WINW) * 8 + (bidx & 7);
            inds[blk * KSIM + sel] =
                (hr + drx - VRAD) * NPOS + (wr + dcx - VRAD);
        }
        __syncthreads();
        int otid = (bidx >> 3) & 255;
        if (tid == otid) {
            int code = (((bidx >> 3) >> 8) << 3) | (bidx & 7);
            lval = INFD; lidx = 0;
#pragma unroll
            for (int s = 0; s < 3; s++)
#pragma unroll
                for (int c = 0; c < 8; c++) {
                    if (((s << 3) | c) == code) d[s][c] = INFD;
                    if (d[s][c] < lval) { lval = d[s][c]; lidx = (s << 3) | c; }
                }
        }
    }
}

// ---------------------------------------------------------------------------
// Stage 2a: per-group solve. NEW: patches staged once in LDS (Yp), Q-build
// via aligned float4 LDS dots (62 b128 + 124 FMA per entry vs 242 global
// gathers). 4 groups/block, ~37 KB LDS -> 4 blocks/CU.
// ---------------------------------------------------------------------------
__global__ __launch_bounds__(256)
void dn_solve(const float* __restrict__ y, const int* __restrict__ inds,
              float* __restrict__ thW)
{
    __shared__ float Yp[4][16][124];     // 31.7 KB (pad 121..123 = 0)
    __shared__ float Qs[4][16][17];
    __shared__ float s1[4][16];
    __shared__ float s2[4];
    __shared__ float wl[4][16];
    __shared__ short pr_[4][16], pc_[4][16];

    const int blk = blockIdx.x;          // 1600 blocks
    const int tid = threadIdx.x;
    const int g0 = blk * 4;

    if (tid < 64) {
        int gq = tid >> 4, m = tid & 15;
        int idx = inds[(g0 + gq) * KSIM + m];
        pr_[gq][m] = (short)(idx / NPOS);
        pc_[gq][m] = (short)(idx % NPOS);
    }
    if (tid < 192) {                     // zero the 3-float pad per row
        int gq = tid / 48, m = (tid / 3) % 16, e = tid % 3;
        Yp[gq][m][121 + e] = 0.f;
    }
    __syncthreads();

    // stage patches: 4*16*121 = 7744 elems, coalesced within 11-elem rows
    for (int t = tid; t < 4 * 16 * 121; t += 256) {
        int gq = t / 1936, m = (t / 121) % 16, j = t % 121;
        int a = j / PP, b = j % PP;
        const float* img = y + ((g0 + gq) / (HREF * WREF)) * HH * WW;
        Yp[gq][m][j] = img[((int)pr_[gq][m] + a) * WW + (int)pc_[gq][m] + b];
    }
    __syncthreads();

    // Q build from LDS: 4*136 entries, float4 dots
    for (int t = tid; t < 4 * 136; t += 256) {
        int gq = t / 136, e = t % 136;
        int i = (int)((sqrtf(8.f * (float)e + 1.f) - 1.f) * 0.5f + 1e-4f);
        int j = e - i * (i + 1) / 2;
        const float4* Yi = reinterpret_cast<const float4*>(&Yp[gq][i][0]);
        const float4* Yj = reinterpret_cast<const float4*>(&Yp[gq][j][0]);
        float s = (i == j) ? EPS_E : 0.f;
#pragma unroll
        for (int q = 0; q < 31; q++) {
            float4 xi = Yi[q], xj = Yj[q];
            s += xi.x * xj.x; s += xi.y * xj.y;
            s += xi.z * xj.z; s += xi.w * xj.w;
        }
        Qs[gq][i][j] = s;
        Qs[gq][j][i] = s;
    }
    __syncthreads();

    // lockstep Gauss-Jordan: thread = (gq, ii, 4-entry j strip)
    const int gq = tid >> 6, ii = (tid >> 2) & 15, jq = tid & 3;
    for (int ks = 0; ks < 16; ks++) {
        float fA = Qs[gq][ii][ks];
        float pv = Qs[gq][ks][ks];
        float rk[4], aij[4];
#pragma unroll
        for (int q = 0; q < 4; q++) {
            rk[q]  = Qs[gq][ks][jq * 4 + q];
            aij[q] = Qs[gq][ii][jq * 4 + q];
        }
        __syncthreads();
        float inv = 1.f / pv;
#pragma unroll
        for (int q = 0; q < 4; q++) {
            int jj = jq * 4 + q;
            float nv;
            if (ii == ks) nv = (jj == ks) ? inv : rk[q] * inv;
            else          nv = (jj == ks) ? -fA * inv : aij[q] - fA * rk[q] * inv;
            Qs[gq][ii][jj] = nv;
        }
        __syncthreads();
    }

    if (jq == 0) {
        float s = 0.f;
#pragma unroll
        for (int b = 0; b < 16; b++) s += Qs[gq][ii][b];
        s1[gq][ii] = s;
    }
    __syncthreads();
    if (ii == 0 && jq == 0) {
        float s = 0.f;
#pragma unroll
        for (int a = 0; a < 16; a++) s += s1[gq][a];
        s2[gq] = s;
    }
    __syncthreads();
    {
        float s1i = s1[gq][ii];
#pragma unroll
        for (int q = 0; q < 4; q++) {
            int jj = jq * 4 + q;
            float t2 = ((ii == jj) ? 1.f : 0.f)
                     - (Qs[gq][ii][jj] - s1i * s1[gq][jj] / s2[gq]) * DE_C;
            Qs[gq][ii][jj] = t2;
        }
    }
    __syncthreads();
    if (jq == 1) {
        float s = 0.f;
#pragma unroll
        for (int m = 0; m < 16; m++) { float t2 = Qs[gq][m][ii]; s += t2 * t2; }
        s = fminf(fmaxf(s, 1.f / 16.f), 1.f);
        wl[gq][ii] = 1.f / s;
    }
    __syncthreads();

    for (int t = tid; t < 4 * THREC; t += 256) {
        int gg = t / THREC, e = t % THREC;
        float v;
        if (e < 136) {
            int i = (int)((sqrtf(8.f * (float)e + 1.f) - 1.f) * 0.5f + 1e-4f);
            int j = e - i * (i + 1) / 2;
            v = Qs[gg][i][j];
        } else {
            v = wl[gg][e - 136];
        }
        thW[(size_t)(g0 + gg) * THREC + e] = v;
    }
}

// ---------------------------------------------------------------------------
// Stage 2b: tiled scatter. NEW: thread = (g, px) — yv loaded ONCE per
// (g,px) (8x fewer gathers than R11); theta*w staged row-major (Athw) so
// the m-step is 4 aligned b128 broadcast reads + 16 FMA. 76.6KB -> 2/CU.
// ---------------------------------------------------------------------------
__global__ __launch_bounds__(512)
void dn_scatter(const float* __restrict__ y, const int* __restrict__ inds,
                const float* __restrict__ thW, float2* __restrict__ nd, int R)
{
    __shared__ float2 acc[84][85];        // 57.1 KB
    __shared__ float  Athw[16][16][16];   // 16.4 KB  A[m][r] = theta*w
    __shared__ float  wlS[16][16];        // 1 KB
    __shared__ int    pOff[16][16];       // 1 KB  (pr-r0)*85+(pc-c0)
    __shared__ int    pBase[16][16];      // 1 KB  pr*128+pc

    const int blk = blockIdx.x;
    const int n  = blk / 100;
    const int tr = blk % 100;
    const int ti = tr / 10, tj = tr % 10;
    const int r0 = 12 * ti - VRAD, c0 = 12 * tj - VRAD;
    const int tid = threadIdx.x;
    const float* img = y + n * HH * WW;

    if (tid < 256) {
        int g = tid >> 4, m = tid & 15;
        int gg = n * (HREF * WREF) + (ti * 4 + (g >> 2)) * WREF + (tj * 4 + (g & 3));
        int idx = inds[gg * KSIM + m];
        int pr = idx / NPOS, pc = idx % NPOS;
        pOff[g][m]  = (pr - r0) * 85 + (pc - c0);
        pBase[g][m] = pr * WW + pc;
        wlS[g][m]   = thW[(size_t)gg * THREC + 136 + m];
    }
    __syncthreads();
    for (int t = tid; t < 16 * 256; t += 512) {   // Athw = tri(m,r) * w[r]
        int g = t >> 8, m = (t >> 4) & 15, r = t & 15;
        int gg = n * (HREF * WREF) + (ti * 4 + (g >> 2)) * WREF + (tj * 4 + (g & 3));
        int hi = (m > r) ? m : r, lo = (m > r) ? r : m;
        Athw[g][m][r] = thW[(size_t)gg * THREC + hi * (hi + 1) / 2 + lo] * wlS[g][r];
    }
    for (int t = tid; t < 84 * 85; t += 512)
        ((float2*)acc)[t] = make_float2(0.f, 0.f);
    __syncthreads();

    // xhat + scatter: thread = (g, px); 16*121 = 1936 tasks
    for (int it = 0; it < 4; it++) {
        int task = tid + it * 512;
        if (task < 16 * 121) {
            int g = task / 121, px = task % 121;
            int dra = px / PP, dca = px % PP;
            const int off  = dra * WW + dca;
            const int offA = dra * 85 + dca;
            float xw[16];
#pragma unroll
            for (int r = 0; r < 16; r++) xw[r] = 0.f;
#pragma unroll
            for (int m = 0; m < 16; m++) {
                float yv = img[pBase[g][m] + off];
                const float4* Arow = reinterpret_cast<const float4*>(&Athw[g][m][0]);
                float4 A0 = Arow[0], A1 = Arow[1], A2 = Arow[2], A3 = Arow[3];
                xw[0]  += A0.x * yv; xw[1]  += A0.y * yv;
                xw[2]  += A0.z * yv; xw[3]  += A0.w * yv;
                xw[4]  += A1.x * yv; xw[5]  += A1.y * yv;
                xw[6]  += A1.z * yv; xw[7]  += A1.w * yv;
                xw[8]  += A2.x * yv; xw[9]  += A2.y * yv;
                xw[10] += A2.z * yv; xw[11] += A2.w * yv;
                xw[12] += A3.x * yv; xw[13] += A3.y * yv;
                xw[14] += A3.z * yv; xw[15] += A3.w * yv;
            }
#pragma unroll
            for (int r = 0; r < 16; r++) {
                float* cell = (float*)acc + 2 * (pOff[g][r] + offA);
                __hip_atomic_fetch_add(cell,     xw[r],
                    __ATOMIC_RELAXED, __HIP_MEMORY_SCOPE_WORKGROUP);
                __hip_atomic_fetch_add(cell + 1, wlS[g][r],
                    __ATOMIC_RELAXED, __HIP_MEMORY_SCOPE_WORKGROUP);
            }
        }
    }
    __syncthreads();

    float2* ndI = nd + ((size_t)(blk & (R - 1)) * NIMG + n) * HH * WW;
    for (int t = tid; t < 84 * 84; t += 512) {
        int rr = t / 84, cc = t % 84;
        float2 vv = acc[rr][cc];
        if (vv.y != 0.f) {
            int px = (r0 + rr) * WW + (c0 + cc);
#if defined(__has_builtin) && __has_builtin(__builtin_amdgcn_global_atomic_fadd_v2f32)
            typedef float v2f __attribute__((ext_vector_type(2)));
            __builtin_amdgcn_global_atomic_fadd_v2f32((v2f*)&ndI[px], (v2f){vv.x, vv.y});
#else
            atomicAdd(&ndI[px].x, vv.x);
            atomicAdd(&ndI[px].y, vv.y);
#endif
        }
    }
}

// ---------------------------------------------------------------------------
// Stage 4: out = sum_r num_r / sum_r den_r
// ---------------------------------------------------------------------------
__global__ __launch_bounds__(256)
void fin_kernel(const float2* __restrict__ nd, float* __restrict__ out, int R)
{
    int t = blockIdx.x * 256 + threadIdx.x;
    if (t < NIMG * HH * WW) {
        float sn = 0.f, sd = 0.f;
        for (int r = 0; r < R; r++) {
            float2 vv = nd[(size_t)r * NIMG * HH * WW + t];
            sn += vv.x; sd += vv.y;
        }
        out[t] = sn / sd;
    }
}

extern "C" void kernel_launch(void* const* d_in, const int* in_sizes, int n_in,
                              void* d_out, int out_size, void* d_ws, size_t ws_size,
                              hipStream_t stream)
{
    const float* y = (const float*)d_in[0];
    float* out = (float*)d_out;

    size_t perRep = (size_t)NIMG * HH * WW * sizeof(float2);   // 524288
    size_t indsB  = (size_t)NGROUP * KSIM * sizeof(int);       // 409600
    size_t thWB   = (size_t)NGROUP * THREC * sizeof(float);    // 3891200
    int R = 1;
    while (R < 4 && perRep * (size_t)(R * 2) + indsB + thWB <= ws_size) R <<= 1;

    float2* nd   = (float2*)d_ws;
    int*    inds = (int*)((char*)d_ws + perRep * (size_t)R);
    float*  thW  = (float*)((char*)inds + indsB);

    hipMemsetAsync(nd, 0, perRep * (size_t)R, stream);
    bm_kernel<<<NGROUP, 256, 0, stream>>>(y, inds);
    dn_solve<<<NGROUP / 4, 256, 0, stream>>>(y, inds, thW);
    dn_scatter<<<NIMG * 100, 512, 0, stream>>>(y, inds, thW, nd, R);
    fin_kernel<<<(NIMG * HH * WW + 255) / 256, 256, 0, stream>>>(nd, out, R);
}